// Round 8
// baseline (436.585 us; speedup 1.0000x reference)
//
#include <hip/hip_runtime.h>

typedef long long i64;
typedef unsigned int uint;
typedef unsigned long long u64;
typedef __attribute__((ext_vector_type(8))) short bf16x8;
typedef __attribute__((ext_vector_type(4))) float f32x4;

#define NU 100000
#define NP 100000
#define NSEG 300000   // pub dst' [0,NP), com [NP,2NP), ucu [2NP,2NP+NU)
#define LBKT 10
#define NBKT 304        // array sizing (>= NBKT_USED, padded)
#define NBKT_USED 293   // ceil(300000/1024)
#define FRONT_PRE 32
#define FRONT_CVT 18750 // NU*48/256

// ---------------- bf16 helpers ----------------
__device__ __forceinline__ uint f2b2(float x, float y) {
    uint ux = __float_as_uint(x), uy = __float_as_uint(y);
    ux = (ux + 0x7FFFu + ((ux >> 16) & 1u)) >> 16;
    uy = (uy + 0x7FFFu + ((uy >> 16) & 1u)) >> 16;
    return ux | (uy << 16);
}
__device__ __forceinline__ float blo(uint a) { return __uint_as_float(a << 16); }
__device__ __forceinline__ float bhi(uint a) { return __uint_as_float(a & 0xFFFF0000u); }

// ---------------- front: prepack | cvt | bucket-hist (fused, independent) ------
__global__ __launch_bounds__(256) void k_front(
    const float* __restrict__ W_pub, const float* __restrict__ W_com,
    const float* __restrict__ W_ecom, const float* __restrict__ W_conv,
    uint4* __restrict__ WpkP, uint4* __restrict__ WpkC, uint4* __restrict__ WpkZ,
    const float* __restrict__ hu, const float* __restrict__ ctx,
    uint* __restrict__ hu2, uint* __restrict__ ctx2,
    const int* __restrict__ pd, int n0, const int* __restrict__ cd, int n1,
    const int* __restrict__ ud, int n2, int* __restrict__ bcnt, int total)
{
    __shared__ int bh[NBKT];
    int bid = blockIdx.x;
    if (bid < FRONT_PRE) {
        int gkt = bid >> 1;
        int sub = (bid & 1) * 256 + threadIdx.x;   // ct*64+lane
        int lane = sub & 63, ct = sub >> 6;
        int r = lane & 15, g = lane >> 4;
        const float* W; uint4* dst; int skt, dkt; float scale;
        if (gkt < 4)       { W = W_pub;              dst = WpkP; skt = gkt;      dkt = skt;     scale = 1.0f; }
        else if (gkt < 8)  { W = W_com;              dst = WpkC; skt = gkt - 4;  dkt = skt;     scale = 0.7f; }
        else if (gkt < 10) { W = W_ecom;             dst = WpkC; skt = gkt - 8;  dkt = skt + 4; scale = 0.3f; }
        else if (gkt < 14) { W = W_conv;             dst = WpkZ; skt = gkt - 10; dkt = skt;     scale = 1.0f; }
        else               { W = W_conv + 128 * 128; dst = WpkZ; skt = gkt - 14; dkt = skt + 4; scale = 1.0f; }
        float v[8];
#pragma unroll
        for (int jj = 0; jj < 8; ++jj)
            v[jj] = W[(i64)(skt * 32 + g * 8 + jj) * 128 + ct * 16 + r] * scale;
        uint4 o;
        o.x = f2b2(v[0], v[1]); o.y = f2b2(v[2], v[3]);
        o.z = f2b2(v[4], v[5]); o.w = f2b2(v[6], v[7]);
        dst[(dkt * 8 + ct) * 64 + lane] = o;
        return;
    }
    bid -= FRONT_PRE;
    if (bid < FRONT_CVT) {
        int t = bid * 256 + threadIdx.x;
        if (t < NU * 32) {
            float4 v = *(const float4*)(hu + (i64)t * 4);
            uint2 o; o.x = f2b2(v.x, v.y); o.y = f2b2(v.z, v.w);
            *(uint2*)(hu2 + (i64)t * 2) = o;
        } else {
            t -= NU * 32;
            float4 v = *(const float4*)(ctx + (i64)t * 4);
            uint2 o; o.x = f2b2(v.x, v.y); o.y = f2b2(v.z, v.w);
            *(uint2*)(ctx2 + (i64)t * 2) = o;
        }
        return;
    }
    bid -= FRONT_CVT;
    // ---- bucket-level histogram ----
    for (int i = threadIdx.x; i < NBKT; i += 256) bh[i] = 0;
    __syncthreads();
    int e0 = bid * 4096;
#pragma unroll
    for (int i = 0; i < 16; ++i) {
        int e = e0 + i * 256 + threadIdx.x;
        if (e < total) {
            int dp;
            if (e < n0) dp = pd[e];
            else if (e < n0 + n1) dp = NP + cd[e - n0];
            else dp = 2 * NP + ud[e - n0 - n1];
            atomicAdd(&bh[dp >> LBKT], 1);
        }
    }
    __syncthreads();
    for (int i = threadIdx.x; i < NBKT_USED; i += 256)
        if (bh[i]) atomicAdd(bcnt + i, bh[i]);
}

// ---------------- tiny scan: bucket counts -> bases + cursors ----------------
__global__ __launch_bounds__(512) void k_scanb(
    const int* __restrict__ bcnt, int* __restrict__ bbase,
    int* __restrict__ gcur, int* __restrict__ rptr)
{
    __shared__ int sm[512];
    int t = threadIdx.x;
    int v = (t < NBKT_USED) ? bcnt[t] : 0;
    sm[t] = v;
    __syncthreads();
    for (int off = 1; off < 512; off <<= 1) {
        int x = (t >= off) ? sm[t - off] : 0;
        __syncthreads();
        sm[t] += x;
        __syncthreads();
    }
    int excl = sm[t] - v;
    if (t <= NBKT_USED) bbase[t] = excl;     // t == NBKT_USED -> total
    if (t < NBKT_USED) gcur[t] = excl;
    if (t == NBKT_USED) rptr[NSEG] = excl;   // total
}

// pass A (fused with z-GEMM): bucket records (src|dst'<<17|eid<<36) + MFMA z path
#define TILE_A 4096
__global__ __launch_bounds__(256) void k_bucketA_zgemm(
    const int* __restrict__ ps, const int* __restrict__ pd, int n0,
    const int* __restrict__ cs, const int* __restrict__ cd, int n1,
    const int* __restrict__ us, const int* __restrict__ ud, int n2,
    int* __restrict__ gcur, u64* __restrict__ recs, int total, int nba,
    const uint* __restrict__ hu2, const uint* __restrict__ ctx2,
    const uint4* __restrict__ Wp, const float* __restrict__ bias,
    const float* __restrict__ ln_g, const float* __restrict__ ln_b,
    uint* __restrict__ zout)
{
    if (blockIdx.x < (unsigned)nba) {
        // ------- bucketA: scatter packed records into dst-buckets -------
        __shared__ int hist[NBKT];
        __shared__ int base[NBKT];
        int t0 = blockIdx.x * TILE_A;
        for (int i = threadIdx.x; i < NBKT; i += 256) hist[i] = 0;
        __syncthreads();
        u64 rec[16];
        int bkt[16];
#pragma unroll
        for (int i = 0; i < 16; ++i) {
            int e = t0 + i * 256 + threadIdx.x;
            if (e < total) {
                int src, dp, eid;
                if (e < n0) { src = ps[e]; dp = pd[e]; eid = 0; }
                else if (e < n0 + n1) { int le = e - n0; src = cs[le]; dp = NP + cd[le]; eid = le; }
                else { int le = e - n0 - n1; src = us[le]; dp = 2 * NP + ud[le]; eid = 0; }
                rec[i] = (u64)src | ((u64)dp << 17) | ((u64)eid << 36);
                bkt[i] = dp >> LBKT;
                atomicAdd(&hist[bkt[i]], 1);
            } else bkt[i] = -1;
        }
        __syncthreads();
        for (int i = threadIdx.x; i < NBKT; i += 256) {
            int h = hist[i];
            base[i] = h ? atomicAdd(gcur + i, h) : 0;
        }
        __syncthreads();
        for (int i = threadIdx.x; i < NBKT; i += 256) hist[i] = 0;
        __syncthreads();
#pragma unroll
        for (int i = 0; i < 16; ++i) {
            if (bkt[i] >= 0) {
                int r = atomicAdd(&hist[bkt[i]], 1);
                recs[(i64)base[bkt[i]] + r] = rec[i];
            }
        }
        return;
    }
    // ------- z-GEMM (K=192) + LayerNorm + ReLU -> bf16 zbuf -------
    const int zb = blockIdx.x - nba;
    const int wave = threadIdx.x >> 6;
    const int lane = threadIdx.x & 63;
    const int row0 = zb * 64 + wave * 16;
    const int r = lane & 15, g = lane >> 4;
    const int arow = min(row0 + r, NU - 1);
    const bf16x8* wp = (const bf16x8*)Wp;

    f32x4 acc[8];
#pragma unroll
    for (int ct = 0; ct < 8; ++ct) acc[ct] = (f32x4){0.f, 0.f, 0.f, 0.f};

    const uint* xu = hu2 + (i64)arow * 64 + g * 4;
#pragma unroll
    for (int kt = 0; kt < 4; ++kt) {
        bf16x8 a = *(const bf16x8*)(xu + kt * 16);
#pragma unroll
        for (int ct = 0; ct < 8; ++ct)
            acc[ct] = __builtin_amdgcn_mfma_f32_16x16x32_bf16(
                a, wp[(kt * 8 + ct) * 64 + lane], acc[ct], 0, 0, 0);
    }
    const uint* xe = ctx2 + (i64)arow * 32 + g * 4;
#pragma unroll
    for (int kt = 0; kt < 2; ++kt) {
        bf16x8 a = *(const bf16x8*)(xe + kt * 16);
#pragma unroll
        for (int ct = 0; ct < 8; ++ct)
            acc[ct] = __builtin_amdgcn_mfma_f32_16x16x32_bf16(
                a, wp[((4 + kt) * 8 + ct) * 64 + lane], acc[ct], 0, 0, 0);
    }

    float bv[8], gv[8], bbv[8];
#pragma unroll
    for (int ct = 0; ct < 8; ++ct) {
        bv[ct] = bias[ct * 16 + r];
        gv[ct] = ln_g[ct * 16 + r];
        bbv[ct] = ln_b[ct * 16 + r];
    }

#pragma unroll
    for (int q = 0; q < 4; ++q) {
        int orow = row0 + g * 4 + q;
        float v[8], s = 0.f;
#pragma unroll
        for (int ct = 0; ct < 8; ++ct) { v[ct] = acc[ct][q] + bv[ct]; s += v[ct]; }
#pragma unroll
        for (int m = 1; m < 16; m <<= 1) s += __shfl_xor(s, m);
        float mu = s * (1.f / 128.f);
        float sq = 0.f;
#pragma unroll
        for (int ct = 0; ct < 8; ++ct) { float d = v[ct] - mu; sq += d * d; }
#pragma unroll
        for (int m = 1; m < 16; m <<= 1) sq += __shfl_xor(sq, m);
        float rs = rsqrtf(sq * (1.f / 128.f) + 1e-5f);
        float o[8];
#pragma unroll
        for (int ct = 0; ct < 8; ++ct)
            o[ct] = fmaxf(0.f, (v[ct] - mu) * rs * gv[ct] + bbv[ct]);
#pragma unroll
        for (int ct = 0; ct < 8; ++ct) {
            float p = __shfl_xor(o[ct], 1);
            if (!(r & 1) && orow < NU)
                zout[(i64)orow * 64 + ct * 8 + (r >> 1)] = f2b2(o[ct], p);
        }
    }
}

// pass B: per-bucket LDS CSR build — writes rptr + ordered esrc4/rec8
__global__ __launch_bounds__(1024) void k_bucketB(
    const u64* __restrict__ recs, const int* __restrict__ bbase, int n0,
    int* __restrict__ rptr, int* __restrict__ esrc4, u64* __restrict__ rec8)
{
    __shared__ int h[1024];
    __shared__ int ss[1024];
    int b = blockIdx.x, tid = threadIdx.x;
    int bb = bbase[b], ne = bbase[b + 1] - bb;
    h[tid] = 0;
    __syncthreads();
    for (int i = tid; i < ne; i += 1024)
        atomicAdd(&h[(int)((recs[bb + i] >> 17) & 1023)], 1);
    __syncthreads();
    int v = h[tid];
    ss[tid] = v;
    __syncthreads();
    for (int off = 1; off < 1024; off <<= 1) {
        int x = (tid >= off) ? ss[tid - off] : 0;
        __syncthreads();
        ss[tid] += x;
        __syncthreads();
    }
    int e0 = ss[tid] - v;       // exclusive
    h[tid] = e0;                // h becomes cursor
    int g = b * 1024 + tid;
    if (g < NSEG) rptr[g] = bb + e0;
    __syncthreads();
    for (int i = tid; i < ne; i += 1024) {
        u64 rec = recs[bb + i];
        int ld = (int)((rec >> 17) & 1023);
        int dp = (int)((rec >> 17) & 0x7FFFF);
        int pos = bb + atomicAdd(&h[ld], 1);
        int src = (int)(rec & 0x1FFFF);
        if (dp >= NP && dp < 2 * NP)
            rec8[pos - n0] = (u64)(uint)src | ((rec >> 36) << 32);
        else
            esrc4[pos] = src;
    }
}

// ---------------- gather bodies: 2 edges in flight per wave (8B/lane) ----------
__device__ __forceinline__ void gather128b_body(
    int row, const uint* __restrict__ feat, const int* __restrict__ rp,
    const int* __restrict__ esrc, int lane,
    float* __restrict__ outf, uint* __restrict__ outb, int divide)
{
    int beg = rp[row], end = rp[row + 1];
    int half = lane >> 5, hl = lane & 31;
    float a0 = 0.f, a1 = 0.f, a2 = 0.f, a3 = 0.f;
    int j = beg;
    for (; j + 16 <= end; j += 16) {
        int s[8]; uint2 a[8];
#pragma unroll
        for (int k = 0; k < 8; ++k) s[k] = esrc[j + half * 8 + k];
#pragma unroll
        for (int k = 0; k < 8; ++k) a[k] = *(const uint2*)(feat + (i64)s[k] * 64 + hl * 2);
#pragma unroll
        for (int k = 0; k < 8; ++k) {
            a0 += blo(a[k].x); a1 += bhi(a[k].x);
            a2 += blo(a[k].y); a3 += bhi(a[k].y);
        }
    }
    if (j < end) {
        int s[8]; uint2 a[8];
#pragma unroll
        for (int k = 0; k < 8; ++k) s[k] = esrc[min(j + half * 8 + k, end - 1)];
#pragma unroll
        for (int k = 0; k < 8; ++k) a[k] = *(const uint2*)(feat + (i64)s[k] * 64 + hl * 2);
#pragma unroll
        for (int k = 0; k < 8; ++k) {
            float m = (j + half * 8 + k < end) ? 1.f : 0.f;
            a0 = fmaf(m, blo(a[k].x), a0); a1 = fmaf(m, bhi(a[k].x), a1);
            a2 = fmaf(m, blo(a[k].y), a2); a3 = fmaf(m, bhi(a[k].y), a3);
        }
    }
    a0 += __shfl_xor(a0, 32); a1 += __shfl_xor(a1, 32);
    a2 += __shfl_xor(a2, 32); a3 += __shfl_xor(a3, 32);
    if (half) return;
    if (outb) {
        uint2 o; o.x = f2b2(a0, a1); o.y = f2b2(a2, a3);
        *(uint2*)(outb + (i64)row * 64 + hl * 2) = o;
        return;
    }
    if (divide) {
        int deg = end - beg;
        float mm = deg > 0 ? 1.f / (float)deg : 0.f;
        a0 *= mm; a1 *= mm; a2 *= mm; a3 *= mm;
    }
    float4 o; o.x = a0; o.y = a1; o.z = a2; o.w = a3;
    *(float4*)(outf + (i64)row * 128 + hl * 4) = o;
}

__device__ __forceinline__ void gather_com_body(
    int row, const uint* __restrict__ hu2, const float* __restrict__ ec,
    const int* __restrict__ rp, const u64* __restrict__ rec8, int ebase, int lane,
    uint* __restrict__ outUb, uint* __restrict__ outEb)
{
    int beg = rp[row], end = rp[row + 1];
    int half = lane >> 5, hl = lane & 31;
    float a0 = 0.f, a1 = 0.f, a2 = 0.f, a3 = 0.f, e0 = 0.f, e1 = 0.f;
    int j = beg;
    for (; j + 16 <= end; j += 16) {
        u64 r[8];
#pragma unroll
        for (int k = 0; k < 8; ++k) r[k] = rec8[j + half * 8 + k - ebase];
        uint2 a[8]; float2 f[8];
#pragma unroll
        for (int k = 0; k < 8; ++k) {
            int s = (int)(uint)r[k];
            int e = (int)(r[k] >> 32);
            a[k] = *(const uint2*)(hu2 + (i64)s * 64 + hl * 2);
            f[k] = *(const float2*)(ec + (i64)e * 64 + hl * 2);
        }
#pragma unroll
        for (int k = 0; k < 8; ++k) {
            a0 += blo(a[k].x); a1 += bhi(a[k].x);
            a2 += blo(a[k].y); a3 += bhi(a[k].y);
            e0 += f[k].x; e1 += f[k].y;
        }
    }
    if (j < end) {
        u64 r[8];
#pragma unroll
        for (int k = 0; k < 8; ++k) r[k] = rec8[min(j + half * 8 + k, end - 1) - ebase];
        uint2 a[8]; float2 f[8];
#pragma unroll
        for (int k = 0; k < 8; ++k) {
            int s = (int)(uint)r[k];
            int e = (int)(r[k] >> 32);
            a[k] = *(const uint2*)(hu2 + (i64)s * 64 + hl * 2);
            f[k] = *(const float2*)(ec + (i64)e * 64 + hl * 2);
        }
#pragma unroll
        for (int k = 0; k < 8; ++k) {
            float m = (j + half * 8 + k < end) ? 1.f : 0.f;
            a0 = fmaf(m, blo(a[k].x), a0); a1 = fmaf(m, bhi(a[k].x), a1);
            a2 = fmaf(m, blo(a[k].y), a2); a3 = fmaf(m, bhi(a[k].y), a3);
            e0 = fmaf(m, f[k].x, e0); e1 = fmaf(m, f[k].y, e1);
        }
    }
    a0 += __shfl_xor(a0, 32); a1 += __shfl_xor(a1, 32);
    a2 += __shfl_xor(a2, 32); a3 += __shfl_xor(a3, 32);
    e0 += __shfl_xor(e0, 32); e1 += __shfl_xor(e1, 32);
    if (half) return;
    uint2 o; o.x = f2b2(a0, a1); o.y = f2b2(a2, a3);
    *(uint2*)(outUb + (i64)row * 64 + hl * 2) = o;
    outEb[(i64)row * 32 + hl] = f2b2(e0, e1);
}

// fused: com | ucu | pub gathers
#define GG (NP * 64 / 256)
__global__ __launch_bounds__(256) void k_gathers3(
    const uint* __restrict__ hu2, const uint* __restrict__ zbuf,
    const float* __restrict__ ec, const int* __restrict__ rptr,
    const int* __restrict__ esrc4, const u64* __restrict__ rec8, int n_pub,
    float* __restrict__ out2, uint* __restrict__ sumP, uint* __restrict__ sumU,
    uint* __restrict__ accEb)
{
    int bid = blockIdx.x;
    int lane = threadIdx.x & 63;
    int wl = threadIdx.x >> 6;
    if (bid < GG) {
        gather_com_body(bid * 4 + wl, hu2, ec, rptr + NP, rec8, n_pub, lane, sumU, accEb);
    } else if (bid < 2 * GG) {
        gather128b_body((bid - GG) * 4 + wl, zbuf, rptr + 2 * NP, esrc4, lane, out2, nullptr, 1);
    } else {
        gather128b_body((bid - 2 * GG) * 4 + wl, hu2, rptr, esrc4, lane, nullptr, sumP, 0);
    }
}

// ---------------- MFMA rowwise GEMM body ----------------
__device__ __forceinline__ void rowgemm_body(
    int bid, int tid, const uint* __restrict__ Xu, const uint* __restrict__ Xe,
    int nktU, int nktE, const uint4* __restrict__ Wp,
    const float* __restrict__ b0, float bs0,
    const float* __restrict__ b1, float bs1,
    const int* __restrict__ rp, float* __restrict__ out, int nrow)
{
    const int wave = tid >> 6;
    const int lane = tid & 63;
    const int row0 = bid * 64 + wave * 16;
    const int r = lane & 15, g = lane >> 4;
    const int arow = min(row0 + r, nrow - 1);
    const bf16x8* wp = (const bf16x8*)Wp;

    f32x4 acc[8];
#pragma unroll
    for (int ct = 0; ct < 8; ++ct) acc[ct] = (f32x4){0.f, 0.f, 0.f, 0.f};

    const int ldu = nktU * 16;
    const uint* xu = Xu + (i64)arow * ldu + g * 4;
    for (int kt = 0; kt < nktU; ++kt) {
        bf16x8 a = *(const bf16x8*)(xu + kt * 16);
#pragma unroll
        for (int ct = 0; ct < 8; ++ct)
            acc[ct] = __builtin_amdgcn_mfma_f32_16x16x32_bf16(
                a, wp[(kt * 8 + ct) * 64 + lane], acc[ct], 0, 0, 0);
    }
    if (nktE) {
        const int lde = nktE * 16;
        const uint* xe = Xe + (i64)arow * lde + g * 4;
        for (int kt = 0; kt < nktE; ++kt) {
            bf16x8 a = *(const bf16x8*)(xe + kt * 16);
#pragma unroll
            for (int ct = 0; ct < 8; ++ct)
                acc[ct] = __builtin_amdgcn_mfma_f32_16x16x32_bf16(
                    a, wp[((nktU + kt) * 8 + ct) * 64 + lane], acc[ct], 0, 0, 0);
        }
    }

    float bv[8];
#pragma unroll
    for (int ct = 0; ct < 8; ++ct) {
        float b = bs0 * b0[ct * 16 + r];
        if (b1) b += bs1 * b1[ct * 16 + r];
        bv[ct] = b;
    }

#pragma unroll
    for (int q = 0; q < 4; ++q) {
        int orow = row0 + g * 4 + q;
        if (orow < nrow) {
            int deg = rp[orow + 1] - rp[orow];
            float m = deg > 0 ? 1.f / (float)deg : 0.f;
            float gate = deg > 0 ? 1.f : 0.f;
#pragma unroll
            for (int ct = 0; ct < 8; ++ct)
                out[(i64)orow * 128 + ct * 16 + r] = gate * fmaf(acc[ct][q], m, bv[ct]);
        }
    }
}

#define GB ((NP + 63) / 64)
__global__ __launch_bounds__(256) void k_rowgemms2(
    const uint* __restrict__ sumP, const uint* __restrict__ sumU,
    const uint* __restrict__ accEb, const uint4* __restrict__ WpkP,
    const uint4* __restrict__ WpkC, const float* __restrict__ b_pub,
    const float* __restrict__ b_com, const float* __restrict__ b_ecom,
    const int* __restrict__ rptr, float* __restrict__ out0, float* __restrict__ out1)
{
    int bid = blockIdx.x;
    if (bid < GB)
        rowgemm_body(bid, threadIdx.x, sumP, nullptr, 4, 0, WpkP,
                     b_pub, 1.0f, nullptr, 0.f, rptr, out0, NP);
    else
        rowgemm_body(bid - GB, threadIdx.x, sumU, accEb, 4, 2, WpkC,
                     b_com, 0.7f, b_ecom, 0.3f, rptr + NP, out1, NP);
}

extern "C" void kernel_launch(void* const* d_in, const int* in_sizes, int n_in,
                              void* d_out, int out_size, void* d_ws, size_t ws_size,
                              hipStream_t stream)
{
    const float* h_user   = (const float*)d_in[0];
    const float* user_ctx = (const float*)d_in[2];
    const float* e_com    = (const float*)d_in[3];
    const int* pub_src = (const int*)d_in[4];
    const int* pub_dst = (const int*)d_in[5];
    const int* com_src = (const int*)d_in[6];
    const int* com_dst = (const int*)d_in[7];
    const int* ucu_src = (const int*)d_in[8];
    const int* ucu_dst = (const int*)d_in[9];
    const float* W_pub  = (const float*)d_in[10];
    const float* b_pub  = (const float*)d_in[11];
    const float* W_com  = (const float*)d_in[12];
    const float* b_com  = (const float*)d_in[13];
    const float* W_conv = (const float*)d_in[14];
    const float* b_conv = (const float*)d_in[15];
    const float* ln_g   = (const float*)d_in[16];
    const float* ln_b   = (const float*)d_in[17];
    const float* W_ecom = (const float*)d_in[18];
    const float* b_ecom = (const float*)d_in[19];

    const int n_pub = in_sizes[4];
    const int n_com = in_sizes[6];
    const int n_ucu = in_sizes[8];
    const int total = n_pub + n_com + n_ucu;

    float* out0 = (float*)d_out;
    float* out1 = out0 + (i64)NP * 128;
    float* out2 = out1 + (i64)NP * 128;

    // ---- ws layout (no overlays; ws is ~1.6 GB) ----
    char* ws = (char*)d_ws;
    i64 off = 0;
    auto alloc = [&](i64 bytes) { i64 p = off; off += (bytes + 15) & ~15LL; return p; };
    uint* hu2   = (uint*)(ws + alloc((i64)NU * 64 * 4));
    uint* ctx2  = (uint*)(ws + alloc((i64)NU * 32 * 4));
    u64* recsA  = (u64*)(ws + alloc((i64)total * 8));
    uint* zbuf  = (uint*)(ws + alloc((i64)NU * 64 * 4));
    uint* sumP  = (uint*)(ws + alloc((i64)NP * 64 * 4));
    uint* sumU  = (uint*)(ws + alloc((i64)NP * 64 * 4));
    uint* accEb = (uint*)(ws + alloc((i64)NP * 32 * 4));
    u64* rec8   = (u64*)(ws + alloc((i64)n_com * 8));
    int* rptr   = (int*)(ws + alloc((i64)(NSEG + 1) * 4));
    int* bcnt   = (int*)(ws + alloc(NBKT * 4));
    int* bbase  = (int*)(ws + alloc((NBKT + 1) * 4));
    int* gcur   = (int*)(ws + alloc(NBKT * 4));
    int* esrc4  = (int*)(ws + alloc((i64)total * 4));
    uint4* WpkP = (uint4*)(ws + alloc(4 * 8 * 64 * 16));   // W_pub, K=128
    uint4* WpkC = (uint4*)(ws + alloc(6 * 8 * 64 * 16));   // [0.7*W_com ; 0.3*W_ecom], K=192
    uint4* WpkZ = (uint4*)(ws + alloc(6 * 8 * 64 * 16));   // W_conv, K=192

    const int nbh = (total + 4095) / 4096;
    const int nba = (total + TILE_A - 1) / TILE_A;
    const int nz  = (NU + 63) / 64;

    // 1. front: prepack | bf16 cvt | bucket hist
    hipMemsetAsync(bcnt, 0, NBKT * 4, stream);
    k_front<<<FRONT_PRE + FRONT_CVT + nbh, 256, 0, stream>>>(
        W_pub, W_com, W_ecom, W_conv, WpkP, WpkC, WpkZ,
        h_user, user_ctx, hu2, ctx2,
        pub_dst, n_pub, com_dst, n_com, ucu_dst, n_ucu, bcnt, total);

    // 2. bucket bases
    k_scanb<<<1, 512, 0, stream>>>(bcnt, bbase, gcur, rptr);

    // 3. bucket scatter of packed records || MFMA z-GEMM+LN+ReLU
    k_bucketA_zgemm<<<nba + nz, 256, 0, stream>>>(
        pub_src, pub_dst, n_pub, com_src, com_dst, n_com,
        ucu_src, ucu_dst, n_ucu, gcur, recsA, total, nba,
        hu2, ctx2, WpkZ, b_conv, ln_g, ln_b, zbuf);

    // 4. per-bucket LDS CSR build -> rptr + esrc4/rec8
    k_bucketB<<<NBKT_USED, 1024, 0, stream>>>(
        recsA, bbase, n_pub, rptr, esrc4, rec8);

    // 5. fused gathers: com | ucu | pub (2-edge-parallel waves)
    k_gathers3<<<3 * GG, 256, 0, stream>>>(
        hu2, zbuf, e_com, rptr, esrc4, rec8, n_pub, out2, sumP, sumU, accEb);

    // 6. fused relation GEMMs
    k_rowgemms2<<<2 * GB, 256, 0, stream>>>(
        sumP, sumU, accEb, WpkP, WpkC, b_pub, b_com, b_ecom, rptr, out0, out1);
}

// Round 9
// 366.522 us; speedup vs baseline: 1.1912x; 1.1912x over previous
//
#include <hip/hip_runtime.h>

typedef long long i64;
typedef unsigned int uint;
typedef unsigned long long u64;
typedef __attribute__((ext_vector_type(8))) short bf16x8;
typedef __attribute__((ext_vector_type(4))) float f32x4;

#define NU 100000
#define NP 100000
#define NSEG 300000   // pub dst' [0,NP), com [NP,2NP), ucu [2NP,2NP+NU)
#define LBKT 10
#define NBKT 304        // array sizing (>= NBKT_USED, padded)
#define NBKT_USED 293   // ceil(300000/1024)
#define FRONT_PRE 32
#define FRONT_CVT 18750 // NU*48/256
#define BSEG 6250       // blocks per relation segment in k_gather_gemm (16 rows/block)

// ---------------- bf16 helpers ----------------
__device__ __forceinline__ uint f2b2(float x, float y) {
    uint ux = __float_as_uint(x), uy = __float_as_uint(y);
    ux = (ux + 0x7FFFu + ((ux >> 16) & 1u)) >> 16;
    uy = (uy + 0x7FFFu + ((uy >> 16) & 1u)) >> 16;
    return ux | (uy << 16);
}
__device__ __forceinline__ float blo(uint a) { return __uint_as_float(a << 16); }
__device__ __forceinline__ float bhi(uint a) { return __uint_as_float(a & 0xFFFF0000u); }

// ---------------- front: prepack | cvt | bucket-hist (fused, independent) ------
__global__ __launch_bounds__(256) void k_front(
    const float* __restrict__ W_pub, const float* __restrict__ W_com,
    const float* __restrict__ W_ecom, const float* __restrict__ W_conv,
    uint4* __restrict__ WpkP, uint4* __restrict__ WpkC, uint4* __restrict__ WpkZ,
    const float* __restrict__ hu, const float* __restrict__ ctx,
    uint* __restrict__ hu2, uint* __restrict__ ctx2,
    const int* __restrict__ pd, int n0, const int* __restrict__ cd, int n1,
    const int* __restrict__ ud, int n2, int* __restrict__ bcnt, int total)
{
    __shared__ int bh[NBKT];
    int bid = blockIdx.x;
    if (bid < FRONT_PRE) {
        int gkt = bid >> 1;
        int sub = (bid & 1) * 256 + threadIdx.x;   // ct*64+lane
        int lane = sub & 63, ct = sub >> 6;
        int r = lane & 15, g = lane >> 4;
        const float* W; uint4* dst; int skt, dkt; float scale;
        if (gkt < 4)       { W = W_pub;              dst = WpkP; skt = gkt;      dkt = skt;     scale = 1.0f; }
        else if (gkt < 8)  { W = W_com;              dst = WpkC; skt = gkt - 4;  dkt = skt;     scale = 0.7f; }
        else if (gkt < 10) { W = W_ecom;             dst = WpkC; skt = gkt - 8;  dkt = skt + 4; scale = 0.3f; }
        else if (gkt < 14) { W = W_conv;             dst = WpkZ; skt = gkt - 10; dkt = skt;     scale = 1.0f; }
        else               { W = W_conv + 128 * 128; dst = WpkZ; skt = gkt - 14; dkt = skt + 4; scale = 1.0f; }
        float v[8];
#pragma unroll
        for (int jj = 0; jj < 8; ++jj)
            v[jj] = W[(i64)(skt * 32 + g * 8 + jj) * 128 + ct * 16 + r] * scale;
        uint4 o;
        o.x = f2b2(v[0], v[1]); o.y = f2b2(v[2], v[3]);
        o.z = f2b2(v[4], v[5]); o.w = f2b2(v[6], v[7]);
        dst[(dkt * 8 + ct) * 64 + lane] = o;
        return;
    }
    bid -= FRONT_PRE;
    if (bid < FRONT_CVT) {
        int t = bid * 256 + threadIdx.x;
        if (t < NU * 32) {
            float4 v = *(const float4*)(hu + (i64)t * 4);
            uint2 o; o.x = f2b2(v.x, v.y); o.y = f2b2(v.z, v.w);
            *(uint2*)(hu2 + (i64)t * 2) = o;
        } else {
            t -= NU * 32;
            float4 v = *(const float4*)(ctx + (i64)t * 4);
            uint2 o; o.x = f2b2(v.x, v.y); o.y = f2b2(v.z, v.w);
            *(uint2*)(ctx2 + (i64)t * 2) = o;
        }
        return;
    }
    bid -= FRONT_CVT;
    // ---- bucket-level histogram ----
    for (int i = threadIdx.x; i < NBKT; i += 256) bh[i] = 0;
    __syncthreads();
    int e0 = bid * 4096;
#pragma unroll
    for (int i = 0; i < 16; ++i) {
        int e = e0 + i * 256 + threadIdx.x;
        if (e < total) {
            int dp;
            if (e < n0) dp = pd[e];
            else if (e < n0 + n1) dp = NP + cd[e - n0];
            else dp = 2 * NP + ud[e - n0 - n1];
            atomicAdd(&bh[dp >> LBKT], 1);
        }
    }
    __syncthreads();
    for (int i = threadIdx.x; i < NBKT_USED; i += 256)
        if (bh[i]) atomicAdd(bcnt + i, bh[i]);
}

// ---------------- tiny scan: bucket counts -> bases + cursors ----------------
__global__ __launch_bounds__(512) void k_scanb(
    const int* __restrict__ bcnt, int* __restrict__ bbase,
    int* __restrict__ gcur, int* __restrict__ rptr)
{
    __shared__ int sm[512];
    int t = threadIdx.x;
    int v = (t < NBKT_USED) ? bcnt[t] : 0;
    sm[t] = v;
    __syncthreads();
    for (int off = 1; off < 512; off <<= 1) {
        int x = (t >= off) ? sm[t - off] : 0;
        __syncthreads();
        sm[t] += x;
        __syncthreads();
    }
    int excl = sm[t] - v;
    if (t <= NBKT_USED) bbase[t] = excl;     // t == NBKT_USED -> total
    if (t < NBKT_USED) gcur[t] = excl;
    if (t == NBKT_USED) rptr[NSEG] = excl;   // total
}

// pass A (fused with z-GEMM): bucket records (src|dst'<<17|eid<<36) + MFMA z path
#define TILE_A 4096
__global__ __launch_bounds__(256) void k_bucketA_zgemm(
    const int* __restrict__ ps, const int* __restrict__ pd, int n0,
    const int* __restrict__ cs, const int* __restrict__ cd, int n1,
    const int* __restrict__ us, const int* __restrict__ ud, int n2,
    int* __restrict__ gcur, u64* __restrict__ recs, int total, int nba,
    const uint* __restrict__ hu2, const uint* __restrict__ ctx2,
    const uint4* __restrict__ Wp, const float* __restrict__ bias,
    const float* __restrict__ ln_g, const float* __restrict__ ln_b,
    uint* __restrict__ zout)
{
    if (blockIdx.x < (unsigned)nba) {
        // ------- bucketA: scatter packed records into dst-buckets -------
        __shared__ int hist[NBKT];
        __shared__ int base[NBKT];
        int t0 = blockIdx.x * TILE_A;
        for (int i = threadIdx.x; i < NBKT; i += 256) hist[i] = 0;
        __syncthreads();
        u64 rec[16];
        int bkt[16];
#pragma unroll
        for (int i = 0; i < 16; ++i) {
            int e = t0 + i * 256 + threadIdx.x;
            if (e < total) {
                int src, dp, eid;
                if (e < n0) { src = ps[e]; dp = pd[e]; eid = 0; }
                else if (e < n0 + n1) { int le = e - n0; src = cs[le]; dp = NP + cd[le]; eid = le; }
                else { int le = e - n0 - n1; src = us[le]; dp = 2 * NP + ud[le]; eid = 0; }
                rec[i] = (u64)src | ((u64)dp << 17) | ((u64)eid << 36);
                bkt[i] = dp >> LBKT;
                atomicAdd(&hist[bkt[i]], 1);
            } else bkt[i] = -1;
        }
        __syncthreads();
        for (int i = threadIdx.x; i < NBKT; i += 256) {
            int h = hist[i];
            base[i] = h ? atomicAdd(gcur + i, h) : 0;
        }
        __syncthreads();
        for (int i = threadIdx.x; i < NBKT; i += 256) hist[i] = 0;
        __syncthreads();
#pragma unroll
        for (int i = 0; i < 16; ++i) {
            if (bkt[i] >= 0) {
                int r = atomicAdd(&hist[bkt[i]], 1);
                recs[(i64)base[bkt[i]] + r] = rec[i];
            }
        }
        return;
    }
    // ------- z-GEMM (K=192) + LayerNorm + ReLU -> bf16 zbuf -------
    const int zb = blockIdx.x - nba;
    const int wave = threadIdx.x >> 6;
    const int lane = threadIdx.x & 63;
    const int row0 = zb * 64 + wave * 16;
    const int r = lane & 15, g = lane >> 4;
    const int arow = min(row0 + r, NU - 1);
    const bf16x8* wp = (const bf16x8*)Wp;

    f32x4 acc[8];
#pragma unroll
    for (int ct = 0; ct < 8; ++ct) acc[ct] = (f32x4){0.f, 0.f, 0.f, 0.f};

    const uint* xu = hu2 + (i64)arow * 64 + g * 4;
#pragma unroll
    for (int kt = 0; kt < 4; ++kt) {
        bf16x8 a = *(const bf16x8*)(xu + kt * 16);
#pragma unroll
        for (int ct = 0; ct < 8; ++ct)
            acc[ct] = __builtin_amdgcn_mfma_f32_16x16x32_bf16(
                a, wp[(kt * 8 + ct) * 64 + lane], acc[ct], 0, 0, 0);
    }
    const uint* xe = ctx2 + (i64)arow * 32 + g * 4;
#pragma unroll
    for (int kt = 0; kt < 2; ++kt) {
        bf16x8 a = *(const bf16x8*)(xe + kt * 16);
#pragma unroll
        for (int ct = 0; ct < 8; ++ct)
            acc[ct] = __builtin_amdgcn_mfma_f32_16x16x32_bf16(
                a, wp[((4 + kt) * 8 + ct) * 64 + lane], acc[ct], 0, 0, 0);
    }

    float bv[8], gv[8], bbv[8];
#pragma unroll
    for (int ct = 0; ct < 8; ++ct) {
        bv[ct] = bias[ct * 16 + r];
        gv[ct] = ln_g[ct * 16 + r];
        bbv[ct] = ln_b[ct * 16 + r];
    }

#pragma unroll
    for (int q = 0; q < 4; ++q) {
        int orow = row0 + g * 4 + q;
        float v[8], s = 0.f;
#pragma unroll
        for (int ct = 0; ct < 8; ++ct) { v[ct] = acc[ct][q] + bv[ct]; s += v[ct]; }
#pragma unroll
        for (int m = 1; m < 16; m <<= 1) s += __shfl_xor(s, m);
        float mu = s * (1.f / 128.f);
        float sq = 0.f;
#pragma unroll
        for (int ct = 0; ct < 8; ++ct) { float d = v[ct] - mu; sq += d * d; }
#pragma unroll
        for (int m = 1; m < 16; m <<= 1) sq += __shfl_xor(sq, m);
        float rs = rsqrtf(sq * (1.f / 128.f) + 1e-5f);
        float o[8];
#pragma unroll
        for (int ct = 0; ct < 8; ++ct)
            o[ct] = fmaxf(0.f, (v[ct] - mu) * rs * gv[ct] + bbv[ct]);
#pragma unroll
        for (int ct = 0; ct < 8; ++ct) {
            float p = __shfl_xor(o[ct], 1);
            if (!(r & 1) && orow < NU)
                zout[(i64)orow * 64 + ct * 8 + (r >> 1)] = f2b2(o[ct], p);
        }
    }
}

// pass B: per-bucket LDS CSR build — writes rptr + ordered esrc4/rec8
__global__ __launch_bounds__(1024) void k_bucketB(
    const u64* __restrict__ recs, const int* __restrict__ bbase, int n0,
    int* __restrict__ rptr, int* __restrict__ esrc4, u64* __restrict__ rec8)
{
    __shared__ int h[1024];
    __shared__ int ss[1024];
    int b = blockIdx.x, tid = threadIdx.x;
    int bb = bbase[b], ne = bbase[b + 1] - bb;
    h[tid] = 0;
    __syncthreads();
    for (int i = tid; i < ne; i += 1024)
        atomicAdd(&h[(int)((recs[bb + i] >> 17) & 1023)], 1);
    __syncthreads();
    int v = h[tid];
    ss[tid] = v;
    __syncthreads();
    for (int off = 1; off < 1024; off <<= 1) {
        int x = (tid >= off) ? ss[tid - off] : 0;
        __syncthreads();
        ss[tid] += x;
        __syncthreads();
    }
    int e0 = ss[tid] - v;       // exclusive
    h[tid] = e0;                // h becomes cursor
    int g = b * 1024 + tid;
    if (g < NSEG) rptr[g] = bb + e0;
    __syncthreads();
    for (int i = tid; i < ne; i += 1024) {
        u64 rec = recs[bb + i];
        int ld = (int)((rec >> 17) & 1023);
        int dp = (int)((rec >> 17) & 0x7FFFF);
        int pos = bb + atomicAdd(&h[ld], 1);
        int src = (int)(rec & 0x1FFFF);
        if (dp >= NP && dp < 2 * NP)
            rec8[pos - n0] = (u64)(uint)src | ((rec >> 36) << 32);
        else
            esrc4[pos] = src;
    }
}

// ---------------- fused gather + relation GEMM ----------------
// blocks [0,BSEG): com -> out1 (K=192 GEMM);  [BSEG,2*BSEG): ucu -> out2 direct;
// [2*BSEG,3*BSEG): pub -> out0 (K=128 GEMM).  16 rows/block, 4 waves x 4 rows.
__global__ __launch_bounds__(256) void k_gather_gemm(
    const uint* __restrict__ hu2, const uint* __restrict__ zbuf,
    const float* __restrict__ ec, const int* __restrict__ rptr,
    const int* __restrict__ esrc4, const u64* __restrict__ rec8, int n_pub,
    const uint4* __restrict__ WpkP, const uint4* __restrict__ WpkC,
    const float* __restrict__ b_pub, const float* __restrict__ b_com,
    const float* __restrict__ b_ecom,
    float* __restrict__ out0, float* __restrict__ out1, float* __restrict__ out2)
{
    __shared__ uint ldsU[16][68];
    __shared__ uint ldsE[16][36];
    const int bid = blockIdx.x;
    const int wave = threadIdx.x >> 6;
    const int lane = threadIdx.x & 63;
    const int r = lane & 15, g = lane >> 4;

    if (bid < BSEG) {
        // ================= com =================
        const int row0 = bid * 16;
        const int* rp = rptr + NP;
        for (int i = 0; i < 4; ++i) {
            int lr = wave * 4 + i;
            int row = row0 + lr;
            int beg = rp[row], end = rp[row + 1];
            float ax = 0.f, ay = 0.f, aE = 0.f;
            int j = beg;
            for (; j + 8 <= end; j += 8) {
                u64 rv[8];
#pragma unroll
                for (int k = 0; k < 8; ++k) rv[k] = rec8[j + k - n_pub];
                uint a[8]; float f[8];
#pragma unroll
                for (int k = 0; k < 8; ++k) {
                    int s = (int)(uint)rv[k];
                    int e = (int)(rv[k] >> 32);
                    a[k] = hu2[(i64)s * 64 + lane];
                    f[k] = ec[(i64)e * 64 + lane];
                }
#pragma unroll
                for (int k = 0; k < 8; ++k) { ax += blo(a[k]); ay += bhi(a[k]); aE += f[k]; }
            }
            if (j < end) {
                int rem = end - j;
                u64 rv[8];
#pragma unroll
                for (int k = 0; k < 8; ++k) rv[k] = rec8[min(j + k, end - 1) - n_pub];
                uint a[8]; float f[8];
#pragma unroll
                for (int k = 0; k < 8; ++k) {
                    int s = (int)(uint)rv[k];
                    int e = (int)(rv[k] >> 32);
                    a[k] = hu2[(i64)s * 64 + lane];
                    f[k] = ec[(i64)e * 64 + lane];
                }
#pragma unroll
                for (int k = 0; k < 8; ++k) {
                    float m = (k < rem) ? 1.f : 0.f;
                    ax = fmaf(m, blo(a[k]), ax); ay = fmaf(m, bhi(a[k]), ay);
                    aE = fmaf(m, f[k], aE);
                }
            }
            ldsU[lr][lane] = f2b2(ax, ay);
            float aE2 = __shfl_xor(aE, 1);
            if (!(lane & 1)) ldsE[lr][lane >> 1] = f2b2(aE, aE2);
        }
        __syncthreads();
        // GEMM phase: wave handles ct = {2*wave, 2*wave+1}, K = 128(U) + 64(E)
        const bf16x8* wp = (const bf16x8*)WpkC;
        const int ct0 = wave * 2;
        f32x4 acc[2];
        acc[0] = (f32x4){0.f, 0.f, 0.f, 0.f};
        acc[1] = (f32x4){0.f, 0.f, 0.f, 0.f};
#pragma unroll
        for (int kt = 0; kt < 4; ++kt) {
            bf16x8 a = *(const bf16x8*)&ldsU[r][kt * 16 + g * 4];
#pragma unroll
            for (int c = 0; c < 2; ++c)
                acc[c] = __builtin_amdgcn_mfma_f32_16x16x32_bf16(
                    a, wp[(kt * 8 + ct0 + c) * 64 + lane], acc[c], 0, 0, 0);
        }
#pragma unroll
        for (int kt = 0; kt < 2; ++kt) {
            bf16x8 a = *(const bf16x8*)&ldsE[r][kt * 16 + g * 4];
#pragma unroll
            for (int c = 0; c < 2; ++c)
                acc[c] = __builtin_amdgcn_mfma_f32_16x16x32_bf16(
                    a, wp[((4 + kt) * 8 + ct0 + c) * 64 + lane], acc[c], 0, 0, 0);
        }
        float bv[2];
#pragma unroll
        for (int c = 0; c < 2; ++c)
            bv[c] = 0.7f * b_com[(ct0 + c) * 16 + r] + 0.3f * b_ecom[(ct0 + c) * 16 + r];
#pragma unroll
        for (int q = 0; q < 4; ++q) {
            int orow = row0 + g * 4 + q;
            int deg = rp[orow + 1] - rp[orow];
            float m = deg > 0 ? 1.f / (float)deg : 0.f;
            float gate = deg > 0 ? 1.f : 0.f;
#pragma unroll
            for (int c = 0; c < 2; ++c)
                out1[(i64)orow * 128 + (ct0 + c) * 16 + r] = gate * fmaf(acc[c][q], m, bv[c]);
        }
    } else if (bid < 2 * BSEG) {
        // ================= ucu (direct out2) =================
        const int row0 = (bid - BSEG) * 16;
        const int* rp = rptr + 2 * NP;
        for (int i = 0; i < 4; ++i) {
            int row = row0 + wave * 4 + i;
            int beg = rp[row], end = rp[row + 1];
            float ax = 0.f, ay = 0.f;
            int j = beg;
            for (; j + 8 <= end; j += 8) {
                int s[8];
#pragma unroll
                for (int k = 0; k < 8; ++k) s[k] = esrc4[j + k];
                uint a[8];
#pragma unroll
                for (int k = 0; k < 8; ++k) a[k] = zbuf[(i64)s[k] * 64 + lane];
#pragma unroll
                for (int k = 0; k < 8; ++k) { ax += blo(a[k]); ay += bhi(a[k]); }
            }
            if (j < end) {
                int rem = end - j;
                int s[8]; uint a[8];
#pragma unroll
                for (int k = 0; k < 8; ++k) s[k] = esrc4[min(j + k, end - 1)];
#pragma unroll
                for (int k = 0; k < 8; ++k) a[k] = zbuf[(i64)s[k] * 64 + lane];
#pragma unroll
                for (int k = 0; k < 8; ++k) {
                    float m = (k < rem) ? 1.f : 0.f;
                    ax = fmaf(m, blo(a[k]), ax); ay = fmaf(m, bhi(a[k]), ay);
                }
            }
            int deg = end - beg;
            float mm = deg > 0 ? 1.f / (float)deg : 0.f;
            float2 o; o.x = ax * mm; o.y = ay * mm;
            *(float2*)(out2 + (i64)row * 128 + lane * 2) = o;
        }
    } else {
        // ================= pub =================
        const int row0 = (bid - 2 * BSEG) * 16;
        const int* rp = rptr;
        for (int i = 0; i < 4; ++i) {
            int lr = wave * 4 + i;
            int row = row0 + lr;
            int beg = rp[row], end = rp[row + 1];
            float ax = 0.f, ay = 0.f;
            int j = beg;
            for (; j + 8 <= end; j += 8) {
                int s[8];
#pragma unroll
                for (int k = 0; k < 8; ++k) s[k] = esrc4[j + k];
                uint a[8];
#pragma unroll
                for (int k = 0; k < 8; ++k) a[k] = hu2[(i64)s[k] * 64 + lane];
#pragma unroll
                for (int k = 0; k < 8; ++k) { ax += blo(a[k]); ay += bhi(a[k]); }
            }
            if (j < end) {
                int rem = end - j;
                int s[8]; uint a[8];
#pragma unroll
                for (int k = 0; k < 8; ++k) s[k] = esrc4[min(j + k, end - 1)];
#pragma unroll
                for (int k = 0; k < 8; ++k) a[k] = hu2[(i64)s[k] * 64 + lane];
#pragma unroll
                for (int k = 0; k < 8; ++k) {
                    float m = (k < rem) ? 1.f : 0.f;
                    ax = fmaf(m, blo(a[k]), ax); ay = fmaf(m, bhi(a[k]), ay);
                }
            }
            ldsU[lr][lane] = f2b2(ax, ay);
        }
        __syncthreads();
        // GEMM phase: K = 128
        const bf16x8* wp = (const bf16x8*)WpkP;
        const int ct0 = wave * 2;
        f32x4 acc[2];
        acc[0] = (f32x4){0.f, 0.f, 0.f, 0.f};
        acc[1] = (f32x4){0.f, 0.f, 0.f, 0.f};
#pragma unroll
        for (int kt = 0; kt < 4; ++kt) {
            bf16x8 a = *(const bf16x8*)&ldsU[r][kt * 16 + g * 4];
#pragma unroll
            for (int c = 0; c < 2; ++c)
                acc[c] = __builtin_amdgcn_mfma_f32_16x16x32_bf16(
                    a, wp[(kt * 8 + ct0 + c) * 64 + lane], acc[c], 0, 0, 0);
        }
        float bv[2];
#pragma unroll
        for (int c = 0; c < 2; ++c) bv[c] = b_pub[(ct0 + c) * 16 + r];
#pragma unroll
        for (int q = 0; q < 4; ++q) {
            int orow = row0 + g * 4 + q;
            int deg = rp[orow + 1] - rp[orow];
            float m = deg > 0 ? 1.f / (float)deg : 0.f;
            float gate = deg > 0 ? 1.f : 0.f;
#pragma unroll
            for (int c = 0; c < 2; ++c)
                out0[(i64)orow * 128 + (ct0 + c) * 16 + r] = gate * fmaf(acc[c][q], m, bv[c]);
        }
    }
}

extern "C" void kernel_launch(void* const* d_in, const int* in_sizes, int n_in,
                              void* d_out, int out_size, void* d_ws, size_t ws_size,
                              hipStream_t stream)
{
    const float* h_user   = (const float*)d_in[0];
    const float* user_ctx = (const float*)d_in[2];
    const float* e_com    = (const float*)d_in[3];
    const int* pub_src = (const int*)d_in[4];
    const int* pub_dst = (const int*)d_in[5];
    const int* com_src = (const int*)d_in[6];
    const int* com_dst = (const int*)d_in[7];
    const int* ucu_src = (const int*)d_in[8];
    const int* ucu_dst = (const int*)d_in[9];
    const float* W_pub  = (const float*)d_in[10];
    const float* b_pub  = (const float*)d_in[11];
    const float* W_com  = (const float*)d_in[12];
    const float* b_com  = (const float*)d_in[13];
    const float* W_conv = (const float*)d_in[14];
    const float* b_conv = (const float*)d_in[15];
    const float* ln_g   = (const float*)d_in[16];
    const float* ln_b   = (const float*)d_in[17];
    const float* W_ecom = (const float*)d_in[18];
    const float* b_ecom = (const float*)d_in[19];

    const int n_pub = in_sizes[4];
    const int n_com = in_sizes[6];
    const int n_ucu = in_sizes[8];
    const int total = n_pub + n_com + n_ucu;

    float* out0 = (float*)d_out;
    float* out1 = out0 + (i64)NP * 128;
    float* out2 = out1 + (i64)NP * 128;

    // ---- ws layout ----
    char* ws = (char*)d_ws;
    i64 off = 0;
    auto alloc = [&](i64 bytes) { i64 p = off; off += (bytes + 15) & ~15LL; return p; };
    uint* hu2   = (uint*)(ws + alloc((i64)NU * 64 * 4));
    uint* ctx2  = (uint*)(ws + alloc((i64)NU * 32 * 4));
    u64* recsA  = (u64*)(ws + alloc((i64)total * 8));
    uint* zbuf  = (uint*)(ws + alloc((i64)NU * 64 * 4));
    u64* rec8   = (u64*)(ws + alloc((i64)n_com * 8));
    int* rptr   = (int*)(ws + alloc((i64)(NSEG + 1) * 4));
    int* bcnt   = (int*)(ws + alloc(NBKT * 4));
    int* bbase  = (int*)(ws + alloc((NBKT + 1) * 4));
    int* gcur   = (int*)(ws + alloc(NBKT * 4));
    int* esrc4  = (int*)(ws + alloc((i64)total * 4));
    uint4* WpkP = (uint4*)(ws + alloc(4 * 8 * 64 * 16));   // W_pub, K=128
    uint4* WpkC = (uint4*)(ws + alloc(6 * 8 * 64 * 16));   // [0.7*W_com ; 0.3*W_ecom], K=192
    uint4* WpkZ = (uint4*)(ws + alloc(6 * 8 * 64 * 16));   // W_conv, K=192

    const int nbh = (total + 4095) / 4096;
    const int nba = (total + TILE_A - 1) / TILE_A;
    const int nz  = (NU + 63) / 64;

    // 1. front: prepack | bf16 cvt | bucket hist
    hipMemsetAsync(bcnt, 0, NBKT * 4, stream);
    k_front<<<FRONT_PRE + FRONT_CVT + nbh, 256, 0, stream>>>(
        W_pub, W_com, W_ecom, W_conv, WpkP, WpkC, WpkZ,
        h_user, user_ctx, hu2, ctx2,
        pub_dst, n_pub, com_dst, n_com, ucu_dst, n_ucu, bcnt, total);

    // 2. bucket bases
    k_scanb<<<1, 512, 0, stream>>>(bcnt, bbase, gcur, rptr);

    // 3. bucket scatter of packed records || MFMA z-GEMM+LN+ReLU
    k_bucketA_zgemm<<<nba + nz, 256, 0, stream>>>(
        pub_src, pub_dst, n_pub, com_src, com_dst, n_com,
        ucu_src, ucu_dst, n_ucu, gcur, recsA, total, nba,
        hu2, ctx2, WpkZ, b_conv, ln_g, ln_b, zbuf);

    // 4. per-bucket LDS CSR build -> rptr + esrc4/rec8
    k_bucketB<<<NBKT_USED, 1024, 0, stream>>>(
        recsA, bbase, n_pub, rptr, esrc4, rec8);

    // 5. fused gathers + relation GEMMs (com | ucu | pub)
    k_gather_gemm<<<3 * BSEG, 256, 0, stream>>>(
        hu2, zbuf, e_com, rptr, esrc4, rec8, n_pub,
        WpkP, WpkC, b_pub, b_com, b_ecom, out0, out1, out2);
}

// Round 10
// 334.202 us; speedup vs baseline: 1.3064x; 1.0967x over previous
//
#include <hip/hip_runtime.h>

typedef long long i64;
typedef unsigned int uint;
typedef unsigned long long u64;
typedef __attribute__((ext_vector_type(8))) short bf16x8;
typedef __attribute__((ext_vector_type(4))) float f32x4;

#define NU 100000
#define NP 100000
#define NSEG 300000   // pub dst' [0,NP), com [NP,2NP), ucu [2NP,2NP+NU)
#define LBKT 10
#define NBKT 304        // array sizing (>= NBKT_USED, padded)
#define NBKT_USED 293   // ceil(300000/1024)
#define CAP 18432       // fixed bucket capacity (mean ~16.4K for com/ucu, +16 sigma)
#define FRONT_PRE 32
#define FRONT_CVT 18750 // NU*48/256
#define BSEG 6250       // blocks per relation segment in k_gather_gemm (16 rows/block)

// ---------------- bf16 helpers ----------------
__device__ __forceinline__ uint f2b2(float x, float y) {
    uint ux = __float_as_uint(x), uy = __float_as_uint(y);
    ux = (ux + 0x7FFFu + ((ux >> 16) & 1u)) >> 16;
    uy = (uy + 0x7FFFu + ((uy >> 16) & 1u)) >> 16;
    return ux | (uy << 16);
}
__device__ __forceinline__ float blo(uint a) { return __uint_as_float(a << 16); }
__device__ __forceinline__ float bhi(uint a) { return __uint_as_float(a & 0xFFFF0000u); }

// ---------------- front: prepack | cvt | gcur-init (fused, independent) ------
__global__ __launch_bounds__(256) void k_front(
    const float* __restrict__ W_pub, const float* __restrict__ W_com,
    const float* __restrict__ W_ecom, const float* __restrict__ W_conv,
    uint4* __restrict__ WpkP, uint4* __restrict__ WpkC, uint4* __restrict__ WpkZ,
    const float* __restrict__ hu, const float* __restrict__ ctx,
    uint* __restrict__ hu2, uint* __restrict__ ctx2, int* __restrict__ gcur)
{
    int bid = blockIdx.x;
    if (bid < FRONT_PRE) {
        int gkt = bid >> 1;
        int sub = (bid & 1) * 256 + threadIdx.x;   // ct*64+lane
        int lane = sub & 63, ct = sub >> 6;
        int r = lane & 15, g = lane >> 4;
        const float* W; uint4* dst; int skt, dkt; float scale;
        if (gkt < 4)       { W = W_pub;              dst = WpkP; skt = gkt;      dkt = skt;     scale = 1.0f; }
        else if (gkt < 8)  { W = W_com;              dst = WpkC; skt = gkt - 4;  dkt = skt;     scale = 0.7f; }
        else if (gkt < 10) { W = W_ecom;             dst = WpkC; skt = gkt - 8;  dkt = skt + 4; scale = 0.3f; }
        else if (gkt < 14) { W = W_conv;             dst = WpkZ; skt = gkt - 10; dkt = skt;     scale = 1.0f; }
        else               { W = W_conv + 128 * 128; dst = WpkZ; skt = gkt - 14; dkt = skt + 4; scale = 1.0f; }
        float v[8];
#pragma unroll
        for (int jj = 0; jj < 8; ++jj)
            v[jj] = W[(i64)(skt * 32 + g * 8 + jj) * 128 + ct * 16 + r] * scale;
        uint4 o;
        o.x = f2b2(v[0], v[1]); o.y = f2b2(v[2], v[3]);
        o.z = f2b2(v[4], v[5]); o.w = f2b2(v[6], v[7]);
        dst[(dkt * 8 + ct) * 64 + lane] = o;
        return;
    }
    bid -= FRONT_PRE;
    if (bid < FRONT_CVT) {
        int t = bid * 256 + threadIdx.x;
        if (t < NU * 32) {
            float4 v = *(const float4*)(hu + (i64)t * 4);
            uint2 o; o.x = f2b2(v.x, v.y); o.y = f2b2(v.z, v.w);
            *(uint2*)(hu2 + (i64)t * 2) = o;
        } else {
            t -= NU * 32;
            float4 v = *(const float4*)(ctx + (i64)t * 4);
            uint2 o; o.x = f2b2(v.x, v.y); o.y = f2b2(v.z, v.w);
            *(uint2*)(ctx2 + (i64)t * 2) = o;
        }
        return;
    }
    // ---- gcur init: fixed bucket bases ----
    int i = threadIdx.x;
    if (i < NBKT_USED) gcur[i] = i * CAP;
    i += 256;
    if (i < NBKT_USED) gcur[i] = i * CAP;
}

// pass A (fused with z-GEMM): bucket records (src|dst'<<17|eid<<36) + MFMA z path
#define TILE_A 4096
__global__ __launch_bounds__(256) void k_bucketA_zgemm(
    const int* __restrict__ ps, const int* __restrict__ pd, int n0,
    const int* __restrict__ cs, const int* __restrict__ cd, int n1,
    const int* __restrict__ us, const int* __restrict__ ud, int n2,
    int* __restrict__ gcur, u64* __restrict__ recs, int total, int nba,
    const uint* __restrict__ hu2, const uint* __restrict__ ctx2,
    const uint4* __restrict__ Wp, const float* __restrict__ bias,
    const float* __restrict__ ln_g, const float* __restrict__ ln_b,
    uint* __restrict__ zout)
{
    if (blockIdx.x < (unsigned)nba) {
        // ------- bucketA: scatter packed records into dst-buckets -------
        __shared__ int hist[NBKT];
        __shared__ int base[NBKT];
        int t0 = blockIdx.x * TILE_A;
        for (int i = threadIdx.x; i < NBKT; i += 256) hist[i] = 0;
        __syncthreads();
        u64 rec[16];
        int bkt[16];
#pragma unroll
        for (int i = 0; i < 16; ++i) {
            int e = t0 + i * 256 + threadIdx.x;
            if (e < total) {
                int src, dp, eid;
                if (e < n0) { src = ps[e]; dp = pd[e]; eid = 0; }
                else if (e < n0 + n1) { int le = e - n0; src = cs[le]; dp = NP + cd[le]; eid = le; }
                else { int le = e - n0 - n1; src = us[le]; dp = 2 * NP + ud[le]; eid = 0; }
                rec[i] = (u64)src | ((u64)dp << 17) | ((u64)eid << 36);
                bkt[i] = dp >> LBKT;
                atomicAdd(&hist[bkt[i]], 1);
            } else bkt[i] = -1;
        }
        __syncthreads();
        for (int i = threadIdx.x; i < NBKT; i += 256) {
            int h = hist[i];
            base[i] = h ? atomicAdd(gcur + i, h) : 0;
        }
        __syncthreads();
        for (int i = threadIdx.x; i < NBKT; i += 256) hist[i] = 0;
        __syncthreads();
#pragma unroll
        for (int i = 0; i < 16; ++i) {
            if (bkt[i] >= 0) {
                int r = atomicAdd(&hist[bkt[i]], 1);
                recs[(i64)base[bkt[i]] + r] = rec[i];
            }
        }
        return;
    }
    // ------- z-GEMM (K=192) + LayerNorm + ReLU -> bf16 zbuf -------
    const int zb = blockIdx.x - nba;
    const int wave = threadIdx.x >> 6;
    const int lane = threadIdx.x & 63;
    const int row0 = zb * 64 + wave * 16;
    const int r = lane & 15, g = lane >> 4;
    const int arow = min(row0 + r, NU - 1);
    const bf16x8* wp = (const bf16x8*)Wp;

    f32x4 acc[8];
#pragma unroll
    for (int ct = 0; ct < 8; ++ct) acc[ct] = (f32x4){0.f, 0.f, 0.f, 0.f};

    const uint* xu = hu2 + (i64)arow * 64 + g * 4;
#pragma unroll
    for (int kt = 0; kt < 4; ++kt) {
        bf16x8 a = *(const bf16x8*)(xu + kt * 16);
#pragma unroll
        for (int ct = 0; ct < 8; ++ct)
            acc[ct] = __builtin_amdgcn_mfma_f32_16x16x32_bf16(
                a, wp[(kt * 8 + ct) * 64 + lane], acc[ct], 0, 0, 0);
    }
    const uint* xe = ctx2 + (i64)arow * 32 + g * 4;
#pragma unroll
    for (int kt = 0; kt < 2; ++kt) {
        bf16x8 a = *(const bf16x8*)(xe + kt * 16);
#pragma unroll
        for (int ct = 0; ct < 8; ++ct)
            acc[ct] = __builtin_amdgcn_mfma_f32_16x16x32_bf16(
                a, wp[((4 + kt) * 8 + ct) * 64 + lane], acc[ct], 0, 0, 0);
    }

    float bv[8], gv[8], bbv[8];
#pragma unroll
    for (int ct = 0; ct < 8; ++ct) {
        bv[ct] = bias[ct * 16 + r];
        gv[ct] = ln_g[ct * 16 + r];
        bbv[ct] = ln_b[ct * 16 + r];
    }

#pragma unroll
    for (int q = 0; q < 4; ++q) {
        int orow = row0 + g * 4 + q;
        float v[8], s = 0.f;
#pragma unroll
        for (int ct = 0; ct < 8; ++ct) { v[ct] = acc[ct][q] + bv[ct]; s += v[ct]; }
#pragma unroll
        for (int m = 1; m < 16; m <<= 1) s += __shfl_xor(s, m);
        float mu = s * (1.f / 128.f);
        float sq = 0.f;
#pragma unroll
        for (int ct = 0; ct < 8; ++ct) { float d = v[ct] - mu; sq += d * d; }
#pragma unroll
        for (int m = 1; m < 16; m <<= 1) sq += __shfl_xor(sq, m);
        float rs = rsqrtf(sq * (1.f / 128.f) + 1e-5f);
        float o[8];
#pragma unroll
        for (int ct = 0; ct < 8; ++ct)
            o[ct] = fmaxf(0.f, (v[ct] - mu) * rs * gv[ct] + bbv[ct]);
#pragma unroll
        for (int ct = 0; ct < 8; ++ct) {
            float p = __shfl_xor(o[ct], 1);
            if (!(r & 1) && orow < NU)
                zout[(i64)orow * 64 + ct * 8 + (r >> 1)] = f2b2(o[ct], p);
        }
    }
}

// pass B: per-bucket LDS CSR build — writes rbeg/rend + ordered esrc4/rec8
__global__ __launch_bounds__(1024) void k_bucketB(
    const u64* __restrict__ recs, const int* __restrict__ gcur,
    int* __restrict__ rbeg, int* __restrict__ rend,
    int* __restrict__ esrc4, u64* __restrict__ rec8)
{
    __shared__ int h[1024];
    __shared__ int ss[1024];
    int b = blockIdx.x, tid = threadIdx.x;
    int bfix = b * CAP;
    int ne = gcur[b] - bfix;
    h[tid] = 0;
    __syncthreads();
    for (int i = tid; i < ne; i += 1024)
        atomicAdd(&h[(int)((recs[(i64)bfix + i] >> 17) & 1023)], 1);
    __syncthreads();
    int v = h[tid];
    ss[tid] = v;
    __syncthreads();
    for (int off = 1; off < 1024; off <<= 1) {
        int x = (tid >= off) ? ss[tid - off] : 0;
        __syncthreads();
        ss[tid] += x;
        __syncthreads();
    }
    int e0 = ss[tid] - v;       // exclusive
    h[tid] = e0;                // h becomes cursor
    int g = b * 1024 + tid;
    if (g < NSEG) { rbeg[g] = bfix + e0; rend[g] = bfix + e0 + v; }
    __syncthreads();
    for (int i = tid; i < ne; i += 1024) {
        u64 rec = recs[(i64)bfix + i];
        int ld = (int)((rec >> 17) & 1023);
        int dp = (int)((rec >> 17) & 0x7FFFF);
        int pos = bfix + atomicAdd(&h[ld], 1);
        int src = (int)(rec & 0x1FFFF);
        if (dp >= NP && dp < 2 * NP)
            rec8[pos] = (u64)(uint)src | ((rec >> 36) << 32);
        else
            esrc4[pos] = src;
    }
}

// ---------------- fused gather + relation GEMM ----------------
// blocks [0,BSEG): com -> out1 (K=192 GEMM);  [BSEG,2*BSEG): ucu -> out2 direct;
// [2*BSEG,3*BSEG): pub -> out0 (K=128 GEMM).  16 rows/block, 4 waves x 4 rows.
__global__ __launch_bounds__(256) void k_gather_gemm(
    const uint* __restrict__ hu2, const uint* __restrict__ zbuf,
    const float* __restrict__ ec,
    const int* __restrict__ rbeg, const int* __restrict__ rend,
    const int* __restrict__ esrc4, const u64* __restrict__ rec8,
    const uint4* __restrict__ WpkP, const uint4* __restrict__ WpkC,
    const float* __restrict__ b_pub, const float* __restrict__ b_com,
    const float* __restrict__ b_ecom,
    float* __restrict__ out0, float* __restrict__ out1, float* __restrict__ out2)
{
    __shared__ uint ldsU[16][68];
    __shared__ uint ldsE[16][36];
    const int bid = blockIdx.x;
    const int wave = threadIdx.x >> 6;
    const int lane = threadIdx.x & 63;
    const int r = lane & 15, g = lane >> 4;

    if (bid < BSEG) {
        // ================= com =================
        const int row0 = bid * 16;
        for (int i = 0; i < 4; ++i) {
            int lr = wave * 4 + i;
            int row = NP + row0 + lr;
            int beg = rbeg[row], end = rend[row];
            float ax = 0.f, ay = 0.f, aE = 0.f;
            int j = beg;
            for (; j + 8 <= end; j += 8) {
                u64 rv[8];
#pragma unroll
                for (int k = 0; k < 8; ++k) rv[k] = rec8[j + k];
                uint a[8]; float f[8];
#pragma unroll
                for (int k = 0; k < 8; ++k) {
                    uint soff = ((uint)(uint)rv[k] << 6) | (uint)lane;
                    uint eoff = ((uint)(rv[k] >> 32) << 6) | (uint)lane;
                    a[k] = hu2[soff];
                    f[k] = ec[eoff];
                }
#pragma unroll
                for (int k = 0; k < 8; ++k) { ax += blo(a[k]); ay += bhi(a[k]); aE += f[k]; }
            }
            if (j < end) {
                int rem = end - j;
                u64 rv[8];
#pragma unroll
                for (int k = 0; k < 8; ++k) rv[k] = rec8[min(j + k, end - 1)];
                uint a[8]; float f[8];
#pragma unroll
                for (int k = 0; k < 8; ++k) {
                    uint soff = ((uint)(uint)rv[k] << 6) | (uint)lane;
                    uint eoff = ((uint)(rv[k] >> 32) << 6) | (uint)lane;
                    a[k] = hu2[soff];
                    f[k] = ec[eoff];
                }
#pragma unroll
                for (int k = 0; k < 8; ++k) {
                    float m = (k < rem) ? 1.f : 0.f;
                    ax = fmaf(m, blo(a[k]), ax); ay = fmaf(m, bhi(a[k]), ay);
                    aE = fmaf(m, f[k], aE);
                }
            }
            ldsU[lr][lane] = f2b2(ax, ay);
            float aE2 = __shfl_xor(aE, 1);
            if (!(lane & 1)) ldsE[lr][lane >> 1] = f2b2(aE, aE2);
        }
        __syncthreads();
        // GEMM phase: wave handles ct = {2*wave, 2*wave+1}, K = 128(U) + 64(E)
        const bf16x8* wp = (const bf16x8*)WpkC;
        const int ct0 = wave * 2;
        f32x4 acc[2];
        acc[0] = (f32x4){0.f, 0.f, 0.f, 0.f};
        acc[1] = (f32x4){0.f, 0.f, 0.f, 0.f};
#pragma unroll
        for (int kt = 0; kt < 4; ++kt) {
            bf16x8 a = *(const bf16x8*)&ldsU[r][kt * 16 + g * 4];
#pragma unroll
            for (int c = 0; c < 2; ++c)
                acc[c] = __builtin_amdgcn_mfma_f32_16x16x32_bf16(
                    a, wp[(kt * 8 + ct0 + c) * 64 + lane], acc[c], 0, 0, 0);
        }
#pragma unroll
        for (int kt = 0; kt < 2; ++kt) {
            bf16x8 a = *(const bf16x8*)&ldsE[r][kt * 16 + g * 4];
#pragma unroll
            for (int c = 0; c < 2; ++c)
                acc[c] = __builtin_amdgcn_mfma_f32_16x16x32_bf16(
                    a, wp[((4 + kt) * 8 + ct0 + c) * 64 + lane], acc[c], 0, 0, 0);
        }
        float bv[2];
#pragma unroll
        for (int c = 0; c < 2; ++c)
            bv[c] = 0.7f * b_com[(ct0 + c) * 16 + r] + 0.3f * b_ecom[(ct0 + c) * 16 + r];
#pragma unroll
        for (int q = 0; q < 4; ++q) {
            int orow = row0 + g * 4 + q;
            int deg = rend[NP + orow] - rbeg[NP + orow];
            float m = deg > 0 ? 1.f / (float)deg : 0.f;
            float gate = deg > 0 ? 1.f : 0.f;
#pragma unroll
            for (int c = 0; c < 2; ++c)
                out1[(i64)orow * 128 + (ct0 + c) * 16 + r] = gate * fmaf(acc[c][q], m, bv[c]);
        }
    } else if (bid < 2 * BSEG) {
        // ================= ucu (direct out2) =================
        const int row0 = (bid - BSEG) * 16;
        for (int i = 0; i < 4; ++i) {
            int row = row0 + wave * 4 + i;
            int beg = rbeg[2 * NP + row], end = rend[2 * NP + row];
            float ax = 0.f, ay = 0.f;
            int j = beg;
            for (; j + 8 <= end; j += 8) {
                int s[8];
#pragma unroll
                for (int k = 0; k < 8; ++k) s[k] = esrc4[j + k];
                uint a[8];
#pragma unroll
                for (int k = 0; k < 8; ++k) a[k] = zbuf[(((uint)s[k]) << 6) | (uint)lane];
#pragma unroll
                for (int k = 0; k < 8; ++k) { ax += blo(a[k]); ay += bhi(a[k]); }
            }
            if (j < end) {
                int rem = end - j;
                int s[8]; uint a[8];
#pragma unroll
                for (int k = 0; k < 8; ++k) s[k] = esrc4[min(j + k, end - 1)];
#pragma unroll
                for (int k = 0; k < 8; ++k) a[k] = zbuf[(((uint)s[k]) << 6) | (uint)lane];
#pragma unroll
                for (int k = 0; k < 8; ++k) {
                    float m = (k < rem) ? 1.f : 0.f;
                    ax = fmaf(m, blo(a[k]), ax); ay = fmaf(m, bhi(a[k]), ay);
                }
            }
            int deg = end - beg;
            float mm = deg > 0 ? 1.f / (float)deg : 0.f;
            float2 o; o.x = ax * mm; o.y = ay * mm;
            *(float2*)(out2 + (i64)row * 128 + lane * 2) = o;
        }
    } else {
        // ================= pub =================
        const int row0 = (bid - 2 * BSEG) * 16;
        for (int i = 0; i < 4; ++i) {
            int lr = wave * 4 + i;
            int row = row0 + lr;
            int beg = rbeg[row], end = rend[row];
            float ax = 0.f, ay = 0.f;
            int j = beg;
            for (; j + 8 <= end; j += 8) {
                int s[8];
#pragma unroll
                for (int k = 0; k < 8; ++k) s[k] = esrc4[j + k];
                uint a[8];
#pragma unroll
                for (int k = 0; k < 8; ++k) a[k] = hu2[(((uint)s[k]) << 6) | (uint)lane];
#pragma unroll
                for (int k = 0; k < 8; ++k) { ax += blo(a[k]); ay += bhi(a[k]); }
            }
            if (j < end) {
                int rem = end - j;
                int s[8]; uint a[8];
#pragma unroll
                for (int k = 0; k < 8; ++k) s[k] = esrc4[min(j + k, end - 1)];
#pragma unroll
                for (int k = 0; k < 8; ++k) a[k] = hu2[(((uint)s[k]) << 6) | (uint)lane];
#pragma unroll
                for (int k = 0; k < 8; ++k) {
                    float m = (k < rem) ? 1.f : 0.f;
                    ax = fmaf(m, blo(a[k]), ax); ay = fmaf(m, bhi(a[k]), ay);
                }
            }
            ldsU[lr][lane] = f2b2(ax, ay);
        }
        __syncthreads();
        // GEMM phase: K = 128
        const bf16x8* wp = (const bf16x8*)WpkP;
        const int ct0 = wave * 2;
        f32x4 acc[2];
        acc[0] = (f32x4){0.f, 0.f, 0.f, 0.f};
        acc[1] = (f32x4){0.f, 0.f, 0.f, 0.f};
#pragma unroll
        for (int kt = 0; kt < 4; ++kt) {
            bf16x8 a = *(const bf16x8*)&ldsU[r][kt * 16 + g * 4];
#pragma unroll
            for (int c = 0; c < 2; ++c)
                acc[c] = __builtin_amdgcn_mfma_f32_16x16x32_bf16(
                    a, wp[(kt * 8 + ct0 + c) * 64 + lane], acc[c], 0, 0, 0);
        }
        float bv[2];
#pragma unroll
        for (int c = 0; c < 2; ++c) bv[c] = b_pub[(ct0 + c) * 16 + r];
#pragma unroll
        for (int q = 0; q < 4; ++q) {
            int orow = row0 + g * 4 + q;
            int deg = rend[orow] - rbeg[orow];
            float m = deg > 0 ? 1.f / (float)deg : 0.f;
            float gate = deg > 0 ? 1.f : 0.f;
#pragma unroll
            for (int c = 0; c < 2; ++c)
                out0[(i64)orow * 128 + (ct0 + c) * 16 + r] = gate * fmaf(acc[c][q], m, bv[c]);
        }
    }
}

extern "C" void kernel_launch(void* const* d_in, const int* in_sizes, int n_in,
                              void* d_out, int out_size, void* d_ws, size_t ws_size,
                              hipStream_t stream)
{
    const float* h_user   = (const float*)d_in[0];
    const float* user_ctx = (const float*)d_in[2];
    const float* e_com    = (const float*)d_in[3];
    const int* pub_src = (const int*)d_in[4];
    const int* pub_dst = (const int*)d_in[5];
    const int* com_src = (const int*)d_in[6];
    const int* com_dst = (const int*)d_in[7];
    const int* ucu_src = (const int*)d_in[8];
    const int* ucu_dst = (const int*)d_in[9];
    const float* W_pub  = (const float*)d_in[10];
    const float* b_pub  = (const float*)d_in[11];
    const float* W_com  = (const float*)d_in[12];
    const float* b_com  = (const float*)d_in[13];
    const float* W_conv = (const float*)d_in[14];
    const float* b_conv = (const float*)d_in[15];
    const float* ln_g   = (const float*)d_in[16];
    const float* ln_b   = (const float*)d_in[17];
    const float* W_ecom = (const float*)d_in[18];
    const float* b_ecom = (const float*)d_in[19];

    const int n_pub = in_sizes[4];
    const int n_com = in_sizes[6];
    const int n_ucu = in_sizes[8];
    const int total = n_pub + n_com + n_ucu;

    float* out0 = (float*)d_out;
    float* out1 = out0 + (i64)NP * 128;
    float* out2 = out1 + (i64)NP * 128;

    // ---- ws layout (padded fixed-capacity bucket arrays) ----
    char* ws = (char*)d_ws;
    i64 off = 0;
    auto alloc = [&](i64 bytes) { i64 p = off; off += (bytes + 15) & ~15LL; return p; };
    const i64 PADDED = (i64)NBKT_USED * CAP;               // 5.4M slots
    uint* hu2   = (uint*)(ws + alloc((i64)NU * 64 * 4));
    uint* ctx2  = (uint*)(ws + alloc((i64)NU * 32 * 4));
    u64* recsA  = (u64*)(ws + alloc(PADDED * 8));
    uint* zbuf  = (uint*)(ws + alloc((i64)NU * 64 * 4));
    u64* rec8   = (u64*)(ws + alloc(PADDED * 8));
    int* rbeg   = (int*)(ws + alloc((i64)NSEG * 4));
    int* rend   = (int*)(ws + alloc((i64)NSEG * 4));
    int* gcur   = (int*)(ws + alloc(NBKT * 4));
    int* esrc4  = (int*)(ws + alloc(PADDED * 4));
    uint4* WpkP = (uint4*)(ws + alloc(4 * 8 * 64 * 16));   // W_pub, K=128
    uint4* WpkC = (uint4*)(ws + alloc(6 * 8 * 64 * 16));   // [0.7*W_com ; 0.3*W_ecom], K=192
    uint4* WpkZ = (uint4*)(ws + alloc(6 * 8 * 64 * 16));   // W_conv, K=192

    const int nba = (total + TILE_A - 1) / TILE_A;
    const int nz  = (NU + 63) / 64;

    // 1. front: prepack | bf16 cvt | gcur init
    k_front<<<FRONT_PRE + FRONT_CVT + 1, 256, 0, stream>>>(
        W_pub, W_com, W_ecom, W_conv, WpkP, WpkC, WpkZ,
        h_user, user_ctx, hu2, ctx2, gcur);

    // 2. bucket scatter of packed records || MFMA z-GEMM+LN+ReLU
    k_bucketA_zgemm<<<nba + nz, 256, 0, stream>>>(
        pub_src, pub_dst, n_pub, com_src, com_dst, n_com,
        ucu_src, ucu_dst, n_ucu, gcur, recsA, total, nba,
        hu2, ctx2, WpkZ, b_conv, ln_g, ln_b, zbuf);

    // 3. per-bucket LDS CSR build -> rbeg/rend + esrc4/rec8
    k_bucketB<<<NBKT_USED, 1024, 0, stream>>>(
        recsA, gcur, rbeg, rend, esrc4, rec8);

    // 4. fused gathers + relation GEMMs (com | ucu | pub)
    k_gather_gemm<<<3 * BSEG, 256, 0, stream>>>(
        hu2, zbuf, e_com, rbeg, rend, esrc4, rec8,
        WpkP, WpkC, b_pub, b_com, b_ecom, out0, out1, out2);
}